// Round 3
// baseline (6063.076 us; speedup 1.0000x reference)
//
#include <hip/hip_runtime.h>
#include <hip/hip_bf16.h>
#include <math.h>

// ---- problem constants ----
#define BB 64
#define NN 128
#define DD 512
#define DFF 2048
#define HH 8
#define DHH 64
#define EE 32
#define HID 64
#define LL 4
#define NTOK (BB*NN)          // 8192

typedef __hip_bfloat16 bf16;

__device__ __forceinline__ float b2f(bf16 x) { return __bfloat162float(x); }
__device__ __forceinline__ bf16 f2b(float x) { return __float2bfloat16(x); }
__device__ __forceinline__ float gelu_f(float x) {
    return 0.5f * x * (1.0f + erff(x * 0.7071067811865476f));
}

union F4B8 { float4 f; bf16 h[8]; };

// ---------------- encoder: feats[BN,4] @ enc_W[4,D] + enc_b (f32 in, bf16 out)
__global__ __launch_bounds__(256) void encoder_kernel(
    const float* __restrict__ bs, const float* __restrict__ ins,
    const float* __restrict__ tr, const float* __restrict__ im,
    const float* __restrict__ encW, const float* __restrict__ encB,
    bf16* __restrict__ X)
{
    int i = blockIdx.x * 256 + threadIdx.x;
    if (i >= NTOK * DD) return;
    int d = i & (DD - 1);
    int t = i >> 9;
    float acc = encB[d]
              + bs[t]  * encW[0 * DD + d]
              + ins[t] * encW[1 * DD + d]
              + tr[t]  * encW[2 * DD + d]
              + im[t]  * encW[3 * DD + d];
    X[i] = f2b(acc);
}

// ---------------- mixed-type tiled GEMM ----------------
// C = act(A @ B + bias); A [M,K] bf16 (lda); B: TB (f32 weights or bf16 scratch),
// [K,N] (ldb) or [N,K] if TRANSB; bias f32 [N]; C: TC (bf16 or f32), [M,N] (ldc).
// Group strides (elements) via blockIdx.z.
template<int BM, int BN, int BK, int TM, int TN, int ACT, bool TRANSB, bool HAS_BIAS,
         typename TB, typename TC>
__global__ __launch_bounds__((BM/TM)*(BN/TN)) void gemm_mix(
    const bf16* __restrict__ A, const TB* __restrict__ Bw,
    const float* __restrict__ bias, TC* __restrict__ C,
    int M, int Nc, int K, int lda, int ldb, int ldc,
    long long sAg, long long sBg, long long sbg, long long sCg)
{
    constexpr int NT = (BM/TM)*(BN/TN);
    __shared__ float As[BK][BM + 4];
    __shared__ float Bs[BK][BN + 4];
    const int g = blockIdx.z;
    const bf16* Ag = A + (size_t)g * sAg;
    const TB* Bg = Bw + (size_t)g * sBg;
    TC* Cg = C + (size_t)g * sCg;
    const int m0 = blockIdx.y * BM;
    const int n0 = blockIdx.x * BN;
    const int tid = threadIdx.x;
    const int tx = tid % (BN/TN);
    const int ty = tid / (BN/TN);

    float acc[TM][TN];
#pragma unroll
    for (int i = 0; i < TM; i++)
#pragma unroll
        for (int j = 0; j < TN; j++) acc[i][j] = 0.f;

    for (int k0 = 0; k0 < K; k0 += BK) {
        // A tile: BM x BK, 8-bf16 chunks
        for (int c = tid; c < BM*(BK/8); c += NT) {
            int row = c / (BK/8);
            int k8 = (c % (BK/8)) * 8;
            F4B8 u; u.f = *(const float4*)(Ag + (size_t)(m0 + row) * lda + k0 + k8);
#pragma unroll
            for (int j = 0; j < 8; j++) As[k8 + j][row] = b2f(u.h[j]);
        }
        if constexpr (!TRANSB) {
            if constexpr (sizeof(TB) == 2) {
                for (int c = tid; c < BK*(BN/8); c += NT) {
                    int kk = c / (BN/8);
                    int c8 = (c % (BN/8)) * 8;
                    F4B8 u; u.f = *(const float4*)((const bf16*)Bg + (size_t)(k0 + kk) * ldb + n0 + c8);
#pragma unroll
                    for (int j = 0; j < 8; j++) Bs[kk][c8 + j] = b2f(u.h[j]);
                }
            } else {
                for (int c = tid; c < BK*(BN/4); c += NT) {
                    int kk = c / (BN/4);
                    int c4 = (c % (BN/4)) * 4;
                    alignas(16) float v[4];
                    *(float4*)v = *(const float4*)((const float*)Bg + (size_t)(k0 + kk) * ldb + n0 + c4);
#pragma unroll
                    for (int j = 0; j < 4; j++) Bs[kk][c4 + j] = v[j];
                }
            }
        } else {
            if constexpr (sizeof(TB) == 2) {
                for (int c = tid; c < BN*(BK/8); c += NT) {
                    int col = c / (BK/8);
                    int k8 = (c % (BK/8)) * 8;
                    F4B8 u; u.f = *(const float4*)((const bf16*)Bg + (size_t)(n0 + col) * ldb + k0 + k8);
#pragma unroll
                    for (int j = 0; j < 8; j++) Bs[k8 + j][col] = b2f(u.h[j]);
                }
            } else {
                for (int c = tid; c < BN*(BK/4); c += NT) {
                    int col = c / (BK/4);
                    int k4 = (c % (BK/4)) * 4;
                    alignas(16) float v[4];
                    *(float4*)v = *(const float4*)((const float*)Bg + (size_t)(n0 + col) * ldb + k0 + k4);
#pragma unroll
                    for (int j = 0; j < 4; j++) Bs[k4 + j][col] = v[j];
                }
            }
        }
        __syncthreads();
#pragma unroll
        for (int kk = 0; kk < BK; kk++) {
            float ar[TM], br[TN];
#pragma unroll
            for (int i = 0; i < TM; i += 4)
                *(float4*)&ar[i] = *(const float4*)&As[kk][ty*TM + i];
#pragma unroll
            for (int j = 0; j < TN; j += 4)
                *(float4*)&br[j] = *(const float4*)&Bs[kk][tx*TN + j];
#pragma unroll
            for (int i = 0; i < TM; i++)
#pragma unroll
                for (int j = 0; j < TN; j++)
                    acc[i][j] = fmaf(ar[i], br[j], acc[i][j]);
        }
        __syncthreads();
    }
#pragma unroll
    for (int i = 0; i < TM; i++) {
        int row = m0 + ty*TM + i;
        int col0 = n0 + tx*TN;
        alignas(16) float vout[TN];
#pragma unroll
        for (int j = 0; j < TN; j++) {
            float v = acc[i][j];
            if (HAS_BIAS) v += bias[(size_t)g*sbg + col0 + j];
            if (ACT == 1) v = gelu_f(v);
            vout[j] = v;
        }
        if constexpr (sizeof(TC) == 2) {
            alignas(16) bf16 ho[TN];
#pragma unroll
            for (int j = 0; j < TN; j++) ho[j] = f2b(vout[j]);
            if (TN == 8)
                *(float4*)((bf16*)Cg + (size_t)row * ldc + col0) = *(float4*)ho;
            else
                *(float2*)((bf16*)Cg + (size_t)row * ldc + col0) = *(float2*)ho;
        } else {
#pragma unroll
            for (int j0 = 0; j0 < TN; j0 += 4)
                *(float4*)((float*)Cg + (size_t)row * ldc + col0 + j0) = *(float4*)&vout[j0];
        }
    }
}

// ---------------- fused attention, one block per (b,h) ----------------
__global__ __launch_bounds__(256) void attn_fused_kernel(
    const bf16* __restrict__ Q, const bf16* __restrict__ K,
    const bf16* __restrict__ V, bf16* __restrict__ O)
{
    int bh = blockIdx.x;
    int h = bh & (HH - 1);
    int b = bh >> 3;
    __shared__ bf16 Qs[NN][DHH + 8];
    __shared__ bf16 Ks[NN][DHH + 8];
    __shared__ bf16 Vs[NN][DHH + 8];
    __shared__ float Ss[NN][NN + 1];
    int tid = threadIdx.x;

    for (int c = tid; c < NN * (DHH/8); c += 256) {
        int row = c >> 3, off = (c & 7) * 8;
        size_t gidx = ((size_t)(b*NN + row)) * DD + h*DHH + off;
        *(float4*)(&Qs[row][off]) = *(const float4*)(Q + gidx);
        *(float4*)(&Ks[row][off]) = *(const float4*)(K + gidx);
        *(float4*)(&Vs[row][off]) = *(const float4*)(V + gidx);
    }
    __syncthreads();

    for (int idx = tid; idx < NN*NN; idx += 256) {
        int n = idx >> 7, m = idx & (NN - 1);
        float s = 0.f;
#pragma unroll
        for (int k = 0; k < DHH; k += 2) {
            __hip_bfloat162 qq = *(const __hip_bfloat162*)&Qs[n][k];
            __hip_bfloat162 kk = *(const __hip_bfloat162*)&Ks[m][k];
            s += b2f(qq.x) * b2f(kk.x) + b2f(qq.y) * b2f(kk.y);
        }
        Ss[n][m] = s * 0.125f;
    }
    __syncthreads();

    if (tid < NN) {
        float mx = -1e30f;
#pragma unroll 4
        for (int m = 0; m < NN; m++) mx = fmaxf(mx, Ss[tid][m]);
        float sum = 0.f;
#pragma unroll 4
        for (int m = 0; m < NN; m++) {
            float e = expf(Ss[tid][m] - mx);
            Ss[tid][m] = e; sum += e;
        }
        float inv = 1.0f / sum;
#pragma unroll 4
        for (int m = 0; m < NN; m++) Ss[tid][m] *= inv;
    }
    __syncthreads();

    for (int idx = tid; idx < NN * DHH; idx += 256) {
        int n = idx >> 6, d = idx & (DHH - 1);
        float o = 0.f;
#pragma unroll 4
        for (int m = 0; m < NN; m++)
            o = fmaf(Ss[n][m], b2f(Vs[m][d]), o);
        O[((size_t)(b*NN + n)) * DD + h*DHH + d] = f2b(o);
    }
}

// ---------------- X = LN(X + R) * g + b (bf16 state, f32 params/math) -----
__global__ __launch_bounds__(256) void add_ln_kernel(
    bf16* __restrict__ X, const bf16* __restrict__ R,
    const float* __restrict__ g, const float* __restrict__ bt)
{
    int t = blockIdx.x;
    int tid = threadIdx.x;
    const size_t base = (size_t)t * DD;
    float y0 = b2f(X[base + tid])       + b2f(R[base + tid]);
    float y1 = b2f(X[base + tid + 256]) + b2f(R[base + tid + 256]);
    __shared__ float red[256];
    red[tid] = y0 + y1; __syncthreads();
    for (int off = 128; off > 0; off >>= 1) {
        if (tid < off) red[tid] += red[tid + off];
        __syncthreads();
    }
    float mean = red[0] * (1.0f/512.0f);
    __syncthreads();
    red[tid] = y0*y0 + y1*y1; __syncthreads();
    for (int off = 128; off > 0; off >>= 1) {
        if (tid < off) red[tid] += red[tid + off];
        __syncthreads();
    }
    float var = fmaxf(red[0] * (1.0f/512.0f) - mean*mean, 0.0f);
    float rstd = rsqrtf(var + 1e-5f);
    X[base + tid]       = f2b((y0 - mean) * rstd * g[tid]       + bt[tid]);
    X[base + tid + 256] = f2b((y1 - mean) * rstd * g[tid + 256] + bt[tid + 256]);
}

// ---------------- hyper-network: mod[b,:] (all f32) ----------------
__global__ __launch_bounds__(512) void hyper_kernel(
    const int* __restrict__ idx, const float* __restrict__ emb,
    const float* __restrict__ W1, const float* __restrict__ b1,
    const float* __restrict__ W2, const float* __restrict__ b2,
    float* __restrict__ MODp)
{
    int b = blockIdx.x;
    int t = threadIdx.x;
    __shared__ float instr[EE];
    __shared__ float h1[HID];
    int id = idx[b];
    if (t < EE) instr[t] = emb[id*EE + t];
    __syncthreads();
    if (t < HID) {
        float a = b1[t];
        for (int i = 0; i < EE; i++) a += instr[i] * W1[i*HID + t];
        h1[t] = gelu_f(a);
    }
    __syncthreads();
    float a = b2[t];
    for (int i = 0; i < HID; i++) a += h1[i] * W2[i*DD + t];
    MODp[(size_t)b*DD + t] = a;
}

// ---------------- xm = x * mod[b] ----------------
__global__ __launch_bounds__(256) void xm_kernel(
    const bf16* __restrict__ X, const float* __restrict__ MODp,
    bf16* __restrict__ XM)
{
    int i = blockIdx.x * 256 + threadIdx.x;
    if (i >= NTOK * DD) return;
    int b = i >> 16;        // / (N*D)
    int d = i & (DD - 1);
    XM[i] = f2b(b2f(X[i]) * MODp[b*DD + d]);
}

// ---------------- deltas[b,n] = HE[n,b,:] . W2[n,:] + b2[n] (f32 out) -----
__global__ __launch_bounds__(256) void deltas_kernel(
    const bf16* __restrict__ HE, const float* __restrict__ W2,
    const float* __restrict__ b2, float* __restrict__ out)
{
    int bid = blockIdx.x;       // n*64 + b
    int n = bid >> 6;
    int b = bid & 63;
    int tid = threadIdx.x;
    const bf16* h = HE + ((size_t)n*BB + b) * DD;
    const float* w = W2 + (size_t)n * DD;
    float s = b2f(h[tid])*w[tid] + b2f(h[tid+256])*w[tid+256];
    __shared__ float red[256];
    red[tid] = s; __syncthreads();
    for (int off = 128; off > 0; off >>= 1) {
        if (tid < off) red[tid] += red[tid + off];
        __syncthreads();
    }
    if (tid == 0) out[b*NN + n] = red[0] + b2[n];
}

// ---------------- adj = sigmoid(logits + noise) (all f32) ----------------
__global__ __launch_bounds__(256) void finalize_kernel(
    const float* __restrict__ lg, const float* __restrict__ gn,
    float* __restrict__ out_adj)
{
    int i = blockIdx.x * 256 + threadIdx.x;
    if (i >= BB*NN*NN) return;
    float z = lg[i] + gn[i];
    out_adj[i] = 1.0f / (1.0f + expf(-z));
}

// =========================== host side ===========================
extern "C" void kernel_launch(void* const* d_in, const int* in_sizes, int n_in,
                              void* d_out, int out_size, void* d_ws, size_t ws_size,
                              hipStream_t stream)
{
    const float* base_s = (const float*)d_in[0];
    const float* int_s  = (const float*)d_in[1];
    const float* targ   = (const float*)d_in[2];
    const float* maskv  = (const float*)d_in[3];
    const int*   nidx   = (const int*)  d_in[4];
    const float* gnoise = (const float*)d_in[5];
    const float* encW = (const float*)d_in[6];
    const float* encB = (const float*)d_in[7];
    const float* Wq = (const float*)d_in[8];  const float* bq = (const float*)d_in[9];
    const float* Wk = (const float*)d_in[10]; const float* bk = (const float*)d_in[11];
    const float* Wv = (const float*)d_in[12]; const float* bv = (const float*)d_in[13];
    const float* Wo = (const float*)d_in[14]; const float* bo = (const float*)d_in[15];
    const float* ln1g = (const float*)d_in[16]; const float* ln1b = (const float*)d_in[17];
    const float* Wff1 = (const float*)d_in[18]; const float* bff1 = (const float*)d_in[19];
    const float* Wff2 = (const float*)d_in[20]; const float* bff2 = (const float*)d_in[21];
    const float* ln2g = (const float*)d_in[22]; const float* ln2b = (const float*)d_in[23];
    const float* emb  = (const float*)d_in[24];
    const float* hW1 = (const float*)d_in[25]; const float* hb1 = (const float*)d_in[26];
    const float* hW2 = (const float*)d_in[27]; const float* hb2 = (const float*)d_in[28];
    const float* eW1 = (const float*)d_in[29]; const float* eb1 = (const float*)d_in[30];
    const float* eW2 = (const float*)d_in[31]; const float* eb2 = (const float*)d_in[32];
    const float* dpW = (const float*)d_in[33]; const float* dpB = (const float*)d_in[34];
    const float* dcW = (const float*)d_in[35]; const float* dcB = (const float*)d_in[36];

    float* out_deltas = (float*)d_out;
    float* out_logits = out_deltas + (size_t)BB*NN;
    float* out_adj    = out_logits + (size_t)BB*NN*NN;

    // workspace: 4 x 8MB bf16 buffers + 128KB f32 MOD = 33.7 MB
    const size_t SZ = (size_t)NTOK * DD;     // 4,194,304 elements
    bf16* X  = (bf16*)d_ws;
    bf16* A1 = X  + SZ;
    bf16* A2 = A1 + SZ;
    bf16* A3 = A2 + SZ;
    float* MODp = (float*)(A3 + SZ);

    encoder_kernel<<<(NTOK*DD + 255)/256, 256, 0, stream>>>(
        base_s, int_s, targ, maskv, encW, encB, X);

    for (int l = 0; l < LL; ++l) {
        const float* Wq_l = Wq + (size_t)l*DD*DD; const float* bq_l = bq + (size_t)l*DD;
        const float* Wk_l = Wk + (size_t)l*DD*DD; const float* bk_l = bk + (size_t)l*DD;
        const float* Wv_l = Wv + (size_t)l*DD*DD; const float* bv_l = bv + (size_t)l*DD;
        const float* Wo_l = Wo + (size_t)l*DD*DD; const float* bo_l = bo + (size_t)l*DD;

        gemm_mix<128,128,16,8,8,0,false,true,float,bf16><<<dim3(4,64,1), 256, 0, stream>>>(
            X, Wq_l, bq_l, A1, NTOK, DD, DD, DD, DD, DD, 0,0,0,0);
        gemm_mix<128,128,16,8,8,0,false,true,float,bf16><<<dim3(4,64,1), 256, 0, stream>>>(
            X, Wk_l, bk_l, A2, NTOK, DD, DD, DD, DD, DD, 0,0,0,0);
        gemm_mix<128,128,16,8,8,0,false,true,float,bf16><<<dim3(4,64,1), 256, 0, stream>>>(
            X, Wv_l, bv_l, A3, NTOK, DD, DD, DD, DD, DD, 0,0,0,0);

        attn_fused_kernel<<<BB*HH, 256, 0, stream>>>(A1, A2, A3, A1);

        gemm_mix<128,128,16,8,8,0,false,true,float,bf16><<<dim3(4,64,1), 256, 0, stream>>>(
            A1, Wo_l, bo_l, A2, NTOK, DD, DD, DD, DD, DD, 0,0,0,0);
        add_ln_kernel<<<NTOK, 256, 0, stream>>>(X, A2, ln1g + (size_t)l*DD, ln1b + (size_t)l*DD);

        // token-chunked FFN: 4 chunks of 2048 rows; hidden tile fits A2
        for (int c = 0; c < 4; ++c) {
            gemm_mix<128,128,16,8,8,1,false,true,float,bf16><<<dim3(16,16,1), 256, 0, stream>>>(
                X + (size_t)c*2048*DD, Wff1 + (size_t)l*DD*DFF, bff1 + (size_t)l*DFF,
                A2, 2048, DFF, DD, DD, DFF, DFF, 0,0,0,0);
            gemm_mix<64,64,16,4,4,0,false,true,float,bf16><<<dim3(8,32,1), 256, 0, stream>>>(
                A2, Wff2 + (size_t)l*DFF*DD, bff2 + (size_t)l*DD,
                A3 + (size_t)c*2048*DD, 2048, DD, DFF, DFF, DD, DD, 0,0,0,0);
        }
        add_ln_kernel<<<NTOK, 256, 0, stream>>>(X, A3, ln2g + (size_t)l*DD, ln2b + (size_t)l*DD);
    }

    // hyper-net modulation
    hyper_kernel<<<BB, 512, 0, stream>>>(nidx, emb, hW1, hb1, hW2, hb2, MODp);
    xm_kernel<<<(NTOK*DD + 255)/256, 256, 0, stream>>>(X, MODp, A1);

    // per-node experts (grouped GEMM over n): HE[n][b][e] -> A2
    gemm_mix<64,128,16,4,8,1,false,true,float,bf16><<<dim3(4,1,NN), 256, 0, stream>>>(
        A1, eW1, eb1, A2, BB, DD, DD, /*lda=*/NN*DD, /*ldb=*/DD, /*ldc=*/DD,
        /*sAg=*/DD, /*sBg=*/(long long)DD*DD, /*sbg=*/DD, /*sCg=*/(long long)BB*DD);
    deltas_kernel<<<NN*BB, 256, 0, stream>>>(A2, eW2, eb2, out_deltas);

    // DAG heads
    gemm_mix<128,128,16,8,8,0,false,true,float,bf16><<<dim3(4,64,1), 256, 0, stream>>>(
        X, dpW, dpB, A1, NTOK, DD, DD, DD, DD, DD, 0,0,0,0);
    gemm_mix<128,128,16,8,8,0,false,true,float,bf16><<<dim3(4,64,1), 256, 0, stream>>>(
        X, dcW, dcB, A3, NTOK, DD, DD, DD, DD, DD, 0,0,0,0);
    // logits[b] = P[b] @ C[b]^T, f32 straight into d_out
    gemm_mix<64,64,16,4,4,0,true,false,bf16,float><<<dim3(2,2,BB), 256, 0, stream>>>(
        A1, A3, (const float*)nullptr, out_logits, NN, NN, DD, DD, DD, NN,
        /*sAg=*/(long long)NN*DD, /*sBg=*/(long long)NN*DD, /*sbg=*/0,
        /*sCg=*/(long long)NN*NN);
    finalize_kernel<<<(BB*NN*NN + 255)/256, 256, 0, stream>>>(
        out_logits, gnoise, out_adj);

    (void)in_sizes; (void)n_in; (void)out_size; (void)ws_size;
}

// Round 4
// 1550.117 us; speedup vs baseline: 3.9114x; 3.9114x over previous
//
#include <hip/hip_runtime.h>
#include <hip/hip_bf16.h>
#include <math.h>

// ---- problem constants ----
#define BB 64
#define NN 128
#define DD 512
#define DFF 2048
#define HH 8
#define DHH 64
#define EE 32
#define HID 64
#define LL 4
#define NTOK (BB*NN)          // 8192
#define QBLK 64

typedef __hip_bfloat16 bf16;
typedef __attribute__((ext_vector_type(8))) short short8v;   // 8 bf16 (4 VGPRs)
typedef __attribute__((ext_vector_type(4))) float f32x4v;    // 4 f32 acc

__device__ __forceinline__ float b2f(bf16 x) { return __bfloat162float(x); }
__device__ __forceinline__ bf16 f2b(float x) { return __float2bfloat16(x); }
__device__ __forceinline__ float gelu_f(float x) {
    return 0.5f * x * (1.0f + erff(x * 0.7071067811865476f));
}

// ---------------- weight prep: f32 [G][K][N] -> bf16 [G][N][K] ----------------
__global__ __launch_bounds__(256) void transpose_prep(
    const float* __restrict__ in, bf16* __restrict__ out, int K, int N)
{
    __shared__ float t[32][33];
    int g = blockIdx.z;
    in  += (size_t)g * K * N;
    out += (size_t)g * K * N;
    int n0 = blockIdx.x * 32, k0 = blockIdx.y * 32;
    int tx = threadIdx.x & 31, ty = threadIdx.x >> 5;   // ty in 0..7
#pragma unroll
    for (int i = 0; i < 32; i += 8)
        t[ty + i][tx] = in[(size_t)(k0 + ty + i) * N + n0 + tx];
    __syncthreads();
#pragma unroll
    for (int i = 0; i < 32; i += 8)
        out[(size_t)(n0 + ty + i) * K + k0 + tx] = f2b(t[tx][ty + i]);
}

// ---------------- encoder: feats[BN,4] @ enc_W[4,D] + enc_b ----------------
__global__ __launch_bounds__(256) void encoder_kernel(
    const float* __restrict__ bs, const float* __restrict__ ins,
    const float* __restrict__ tr, const float* __restrict__ im,
    const float* __restrict__ encW, const float* __restrict__ encB,
    bf16* __restrict__ X)
{
    int i = blockIdx.x * 256 + threadIdx.x;
    if (i >= NTOK * DD) return;
    int d = i & (DD - 1);
    int t = i >> 9;
    float acc = encB[d]
              + bs[t]  * encW[0 * DD + d]
              + ins[t] * encW[1 * DD + d]
              + tr[t]  * encW[2 * DD + d]
              + im[t]  * encW[3 * DD + d];
    X[i] = f2b(acc);
}

// ---------------- MFMA GEMM ----------------
// C = act(A @ B + bias). A: bf16 [M,K] (lda, group sAg).
// B: TRANSB -> TB=bf16 [N,K] (ldb = k-stride); else TB=f32 [K,N] (ldb = N-stride).
// C: TC (bf16/f32) [M,N] (ldc). 256 threads = 4 waves in 2x2; wave tile (BM/2)x(BN/2).
// mfma_f32_16x16x32_bf16: A row=lane&15,k=(lane>>4)*8+j; B col=lane&15 same k;
// D col=lane&15, row=(lane>>4)*4+reg   [verified layout]
template<int BM, int BN, int ACT, bool TRANSB, bool HAS_BIAS, typename TB, typename TC>
__global__ __launch_bounds__(256) void mfma_gemm(
    const bf16* __restrict__ A, const TB* __restrict__ Bw,
    const float* __restrict__ bias, TC* __restrict__ C,
    int K, int lda, int ldb, int ldc,
    long long sAg, long long sBg, long long sbg, long long sCg)
{
    constexpr int BK = 32;
    constexpr int LDK = BK + 8;          // 40 bf16 = 80B rows (16B aligned)
    constexpr int MI = BM / 32;          // frags per wave in m
    constexpr int NI = BN / 32;
    __shared__ bf16 As[BM][LDK];
    __shared__ bf16 Bs[BN][LDK];
    const int g = blockIdx.z;
    const bf16* Ag = A + (size_t)g * sAg;
    const TB*   Bg = Bw + (size_t)g * sBg;
    const int m0 = blockIdx.y * BM;
    const int n0 = blockIdx.x * BN;
    const int tid = threadIdx.x;
    const int lane = tid & 63;
    const int wid = tid >> 6;
    const int wm = wid >> 1, wn = wid & 1;
    const int lr = lane & 15;
    const int lq = lane >> 4;

    f32x4v acc[MI][NI];
#pragma unroll
    for (int mi = 0; mi < MI; mi++)
#pragma unroll
        for (int ni = 0; ni < NI; ni++)
            acc[mi][ni] = (f32x4v){0.f, 0.f, 0.f, 0.f};

    for (int k0 = 0; k0 < K; k0 += BK) {
        // stage A: BM x 32 bf16, float4 = 8 bf16 chunks
#pragma unroll
        for (int c = tid; c < BM * 4; c += 256) {
            int row = c >> 2, k8 = (c & 3) << 3;
            *(float4*)&As[row][k8] =
                *(const float4*)(Ag + (size_t)(m0 + row) * lda + k0 + k8);
        }
        if constexpr (TRANSB) {
            // bf16 [N][K]: contiguous, conflict-free
#pragma unroll
            for (int c = tid; c < BN * 4; c += 256) {
                int row = c >> 2, k8 = (c & 3) << 3;
                *(float4*)&Bs[row][k8] =
                    *(const float4*)((const bf16*)Bg + (size_t)(n0 + row) * ldb + k0 + k8);
            }
        } else {
            // f32 [K][N]: transpose + XOR swizzle on k-group
#pragma unroll
            for (int c = tid; c < BK * (BN / 4); c += 256) {
                int kk = c / (BN / 4);
                int n4 = (c % (BN / 4)) * 4;
                float4 v = *(const float4*)((const float*)Bg + (size_t)(k0 + kk) * ldb + n0 + n4);
                int kg = kk >> 3, kw = kk & 7;
                float vv[4] = {v.x, v.y, v.z, v.w};
#pragma unroll
                for (int i = 0; i < 4; i++) {
                    int n = n4 + i;
                    int col = ((kg ^ ((n >> 2) & 3)) << 3) | kw;
                    Bs[n][col] = f2b(vv[i]);
                }
            }
        }
        __syncthreads();
        short8v av[MI], bv[NI];
#pragma unroll
        for (int mi = 0; mi < MI; mi++) {
            int row = wm * (BM / 2) + mi * 16 + lr;
            av[mi] = *(const short8v*)&As[row][lq * 8];
        }
#pragma unroll
        for (int ni = 0; ni < NI; ni++) {
            int row = wn * (BN / 2) + ni * 16 + lr;
            int col = TRANSB ? (lq * 8) : (((lq ^ ((row >> 2) & 3)) << 3));
            bv[ni] = *(const short8v*)&Bs[row][col];
        }
#pragma unroll
        for (int mi = 0; mi < MI; mi++)
#pragma unroll
            for (int ni = 0; ni < NI; ni++)
                acc[mi][ni] = __builtin_amdgcn_mfma_f32_16x16x32_bf16(
                    av[mi], bv[ni], acc[mi][ni], 0, 0, 0);
        __syncthreads();
    }
    // epilogue
    TC* Cg = C + (size_t)g * sCg;
#pragma unroll
    for (int mi = 0; mi < MI; mi++) {
        int rbase = m0 + wm * (BM / 2) + mi * 16 + lq * 4;
#pragma unroll
        for (int ni = 0; ni < NI; ni++) {
            int col = n0 + wn * (BN / 2) + ni * 16 + lr;
            float bvv = HAS_BIAS ? bias[(size_t)g * sbg + col] : 0.f;
#pragma unroll
            for (int r = 0; r < 4; r++) {
                float v = acc[mi][ni][r] + bvv;
                if (ACT == 1) v = gelu_f(v);
                if constexpr (sizeof(TC) == 2)
                    ((bf16*)Cg)[(size_t)(rbase + r) * ldc + col] = f2b(v);
                else
                    ((float*)Cg)[(size_t)(rbase + r) * ldc + col] = v;
            }
        }
    }
}

// ---------------- fused attention, one block per (b,h,half) ----------------
__global__ __launch_bounds__(256) void attn_fused2(
    const bf16* __restrict__ Q, const bf16* __restrict__ K,
    const bf16* __restrict__ V, bf16* __restrict__ O)
{
    int blk = blockIdx.x;               // ((b*H + h)<<1) | half
    int half = blk & 1;
    int h = (blk >> 1) & (HH - 1);
    int b = blk >> 4;
    __shared__ bf16 Qs[QBLK][DHH + 8];
    __shared__ bf16 Ks[NN][DHH + 8];
    __shared__ bf16 Vs[NN][DHH + 8];
    __shared__ float Ss[QBLK][NN + 1];
    int tid = threadIdx.x;

    for (int c = tid; c < NN * 8; c += 256) {
        int row = c >> 3, off = (c & 7) * 8;
        size_t gi = ((size_t)(b * NN + row)) * DD + h * DHH + off;
        *(float4*)&Ks[row][off] = *(const float4*)(K + gi);
        *(float4*)&Vs[row][off] = *(const float4*)(V + gi);
    }
    for (int c = tid; c < QBLK * 8; c += 256) {
        int row = c >> 3, off = (c & 7) * 8;
        size_t gi = ((size_t)(b * NN + half * QBLK + row)) * DD + h * DHH + off;
        *(float4*)&Qs[row][off] = *(const float4*)(Q + gi);
    }
    __syncthreads();

    for (int idx = tid; idx < QBLK * NN; idx += 256) {
        int n = idx >> 7, m = idx & (NN - 1);
        float s = 0.f;
#pragma unroll
        for (int k = 0; k < DHH; k += 2) {
            __hip_bfloat162 qq = *(const __hip_bfloat162*)&Qs[n][k];
            __hip_bfloat162 kk = *(const __hip_bfloat162*)&Ks[m][k];
            s += b2f(qq.x) * b2f(kk.x) + b2f(qq.y) * b2f(kk.y);
        }
        Ss[n][m] = s * 0.125f;
    }
    __syncthreads();

    {   // wave-parallel softmax: 4 threads per row
        int r = tid >> 2, sub = tid & 3;
        float mx = -1e30f;
#pragma unroll 8
        for (int m = sub * 32; m < sub * 32 + 32; m++) mx = fmaxf(mx, Ss[r][m]);
        mx = fmaxf(mx, __shfl_xor(mx, 1, 64));
        mx = fmaxf(mx, __shfl_xor(mx, 2, 64));
        float sum = 0.f;
#pragma unroll 8
        for (int m = sub * 32; m < sub * 32 + 32; m++) {
            float e = expf(Ss[r][m] - mx);
            Ss[r][m] = e; sum += e;
        }
        sum += __shfl_xor(sum, 1, 64);
        sum += __shfl_xor(sum, 2, 64);
        float inv = 1.0f / sum;
#pragma unroll 8
        for (int m = sub * 32; m < sub * 32 + 32; m++) Ss[r][m] *= inv;
    }
    __syncthreads();

    for (int idx = tid; idx < QBLK * DHH; idx += 256) {
        int n = idx >> 6, d = idx & (DHH - 1);
        float o = 0.f;
#pragma unroll 8
        for (int m = 0; m < NN; m++)
            o = fmaf(Ss[n][m], b2f(Vs[m][d]), o);
        O[((size_t)(b * NN + half * QBLK + n)) * DD + h * DHH + d] = f2b(o);
    }
}

// ---------------- X = LN(X + R) * g + b ----------------
__global__ __launch_bounds__(256) void add_ln_kernel(
    bf16* __restrict__ X, const bf16* __restrict__ R,
    const float* __restrict__ g, const float* __restrict__ bt)
{
    int t = blockIdx.x;
    int tid = threadIdx.x;
    const size_t base = (size_t)t * DD;
    float y0 = b2f(X[base + tid])       + b2f(R[base + tid]);
    float y1 = b2f(X[base + tid + 256]) + b2f(R[base + tid + 256]);
    __shared__ float red[256];
    red[tid] = y0 + y1; __syncthreads();
    for (int off = 128; off > 0; off >>= 1) {
        if (tid < off) red[tid] += red[tid + off];
        __syncthreads();
    }
    float mean = red[0] * (1.0f/512.0f);
    __syncthreads();
    red[tid] = y0*y0 + y1*y1; __syncthreads();
    for (int off = 128; off > 0; off >>= 1) {
        if (tid < off) red[tid] += red[tid + off];
        __syncthreads();
    }
    float var = fmaxf(red[0] * (1.0f/512.0f) - mean*mean, 0.0f);
    float rstd = rsqrtf(var + 1e-5f);
    X[base + tid]       = f2b((y0 - mean) * rstd * g[tid]       + bt[tid]);
    X[base + tid + 256] = f2b((y1 - mean) * rstd * g[tid + 256] + bt[tid + 256]);
}

// ---------------- hyper-network ----------------
__global__ __launch_bounds__(512) void hyper_kernel(
    const int* __restrict__ idx, const float* __restrict__ emb,
    const float* __restrict__ W1, const float* __restrict__ b1,
    const float* __restrict__ W2, const float* __restrict__ b2,
    float* __restrict__ MODp)
{
    int b = blockIdx.x;
    int t = threadIdx.x;
    __shared__ float instr[EE];
    __shared__ float h1[HID];
    int id = idx[b];
    if (t < EE) instr[t] = emb[id*EE + t];
    __syncthreads();
    if (t < HID) {
        float a = b1[t];
        for (int i = 0; i < EE; i++) a += instr[i] * W1[i*HID + t];
        h1[t] = gelu_f(a);
    }
    __syncthreads();
    float a = b2[t];
    for (int i = 0; i < HID; i++) a += h1[i] * W2[i*DD + t];
    MODp[(size_t)b*DD + t] = a;
}

// ---------------- xm = x * mod[b] ----------------
__global__ __launch_bounds__(256) void xm_kernel(
    const bf16* __restrict__ X, const float* __restrict__ MODp,
    bf16* __restrict__ XM)
{
    int i = blockIdx.x * 256 + threadIdx.x;
    if (i >= NTOK * DD) return;
    int b = i >> 16;
    int d = i & (DD - 1);
    XM[i] = f2b(b2f(X[i]) * MODp[b*DD + d]);
}

// ---------------- deltas[b,n] = HE[n,b,:] . W2[n,:] + b2[n] ----------------
__global__ __launch_bounds__(256) void deltas_kernel(
    const bf16* __restrict__ HE, const float* __restrict__ W2,
    const float* __restrict__ b2, float* __restrict__ out)
{
    int bid = blockIdx.x;       // n*64 + b
    int n = bid >> 6;
    int b = bid & 63;
    int tid = threadIdx.x;
    const bf16* h = HE + ((size_t)n*BB + b) * DD;
    const float* w = W2 + (size_t)n * DD;
    float s = b2f(h[tid])*w[tid] + b2f(h[tid+256])*w[tid+256];
    __shared__ float red[256];
    red[tid] = s; __syncthreads();
    for (int off = 128; off > 0; off >>= 1) {
        if (tid < off) red[tid] += red[tid + off];
        __syncthreads();
    }
    if (tid == 0) out[b*NN + n] = red[0] + b2[n];
}

// ---------------- adj = sigmoid(logits + noise) ----------------
__global__ __launch_bounds__(256) void finalize_kernel(
    const float* __restrict__ lg, const float* __restrict__ gn,
    float* __restrict__ out_adj)
{
    int i = blockIdx.x * 256 + threadIdx.x;
    if (i >= BB*NN*NN) return;
    float z = lg[i] + gn[i];
    out_adj[i] = 1.0f / (1.0f + expf(-z));
}

// ---------------- host-side GEMM dispatch helper ----------------
template<int BM, int BN, int ACT, bool HB, typename TC>
static inline void launch_gemm(bool p0, dim3 grid, hipStream_t s,
    const bf16* A, const float* Wf, const bf16* Wt, const float* bias, TC* C,
    int K, int lda, int ldbF, int ldbT, int ldc,
    long long sAg, long long sBg, long long sbg, long long sCg)
{
    if (p0)
        mfma_gemm<BM,BN,ACT,true ,HB,bf16 ,TC><<<grid,256,0,s>>>(A, Wt, bias, C, K, lda, ldbT, ldc, sAg,sBg,sbg,sCg);
    else
        mfma_gemm<BM,BN,ACT,false,HB,float,TC><<<grid,256,0,s>>>(A, Wf, bias, C, K, lda, ldbF, ldc, sAg,sBg,sbg,sCg);
}

// =========================== host side ===========================
extern "C" void kernel_launch(void* const* d_in, const int* in_sizes, int n_in,
                              void* d_out, int out_size, void* d_ws, size_t ws_size,
                              hipStream_t stream)
{
    const float* base_s = (const float*)d_in[0];
    const float* int_s  = (const float*)d_in[1];
    const float* targ   = (const float*)d_in[2];
    const float* maskv  = (const float*)d_in[3];
    const int*   nidx   = (const int*)  d_in[4];
    const float* gnoise = (const float*)d_in[5];
    const float* encW = (const float*)d_in[6];
    const float* encB = (const float*)d_in[7];
    const float* Wq = (const float*)d_in[8];  const float* bq = (const float*)d_in[9];
    const float* Wk = (const float*)d_in[10]; const float* bk = (const float*)d_in[11];
    const float* Wv = (const float*)d_in[12]; const float* bv = (const float*)d_in[13];
    const float* Wo = (const float*)d_in[14]; const float* bo = (const float*)d_in[15];
    const float* ln1g = (const float*)d_in[16]; const float* ln1b = (const float*)d_in[17];
    const float* Wff1 = (const float*)d_in[18]; const float* bff1 = (const float*)d_in[19];
    const float* Wff2 = (const float*)d_in[20]; const float* bff2 = (const float*)d_in[21];
    const float* ln2g = (const float*)d_in[22]; const float* ln2b = (const float*)d_in[23];
    const float* emb  = (const float*)d_in[24];
    const float* hW1 = (const float*)d_in[25]; const float* hb1 = (const float*)d_in[26];
    const float* hW2 = (const float*)d_in[27]; const float* hb2 = (const float*)d_in[28];
    const float* eW1 = (const float*)d_in[29]; const float* eb1 = (const float*)d_in[30];
    const float* eW2 = (const float*)d_in[31]; const float* eb2 = (const float*)d_in[32];
    const float* dpW = (const float*)d_in[33]; const float* dpB = (const float*)d_in[34];
    const float* dcW = (const float*)d_in[35]; const float* dcB = (const float*)d_in[36];

    float* out_deltas = (float*)d_out;
    float* out_logits = out_deltas + (size_t)BB*NN;
    float* out_adj    = out_logits + (size_t)BB*NN*NN;

    const size_t SZ = (size_t)NTOK * DD;     // 4,194,304 elements

    // workspace tiering
    const size_t NEED_P2 = 4*SZ*2 + (size_t)BB*DD*4;                    // 33.7 MB
    const size_t NEED_P1 = 6*SZ*2 + (size_t)BB*DD*4;                    // 50.5 MB
    const size_t WT_ELEMS = (size_t)4*LL*DD*DD + 2*(size_t)LL*DD*DFF
                          + (size_t)NN*DD*DD + 2*(size_t)DD*DD;         // 46,661,632
    const size_t NEED_P0 = NEED_P1 + WT_ELEMS*2;                        // ~143.8 MB
    const bool p0  = ws_size >= NEED_P0;
    const bool big = ws_size >= NEED_P1;

    bf16* X = (bf16*)d_ws;
    bf16 *A1, *A2, *A3, *Hid, *Yb;
    float* MODp;
    if (big) {
        bf16* H0 = X + SZ;
        A1 = H0; A2 = H0 + SZ; A3 = H0 + 2*SZ;
        Hid = H0;                    // full 8192 x 2048 hidden
        Yb  = H0 + 4*SZ;             // FFN output / XM
        MODp = (float*)(Yb + SZ);
    } else {
        A1 = X + SZ; A2 = A1 + SZ; A3 = A2 + SZ;
        Hid = A2; Yb = nullptr;
        MODp = (float*)(A3 + SZ);
    }

    // pre-transposed bf16 weights (P0)
    bf16 *wqT=nullptr,*wkT=nullptr,*wvT=nullptr,*woT=nullptr,
         *wf1T=nullptr,*wf2T=nullptr,*e1T=nullptr,*dpT=nullptr,*dcT=nullptr;
    if (p0) {
        bf16* WT = (bf16*)(MODp + (size_t)BB*DD);
        wqT = WT;                         wkT = wqT + (size_t)LL*DD*DD;
        wvT = wkT + (size_t)LL*DD*DD;     woT = wvT + (size_t)LL*DD*DD;
        wf1T = woT + (size_t)LL*DD*DD;    wf2T = wf1T + (size_t)LL*DD*DFF;
        e1T = wf2T + (size_t)LL*DD*DFF;   dpT = e1T + (size_t)NN*DD*DD;
        dcT = dpT + (size_t)DD*DD;

        transpose_prep<<<dim3(DD/32, DD/32, LL), 256, 0, stream>>>(Wq, wqT, DD, DD);
        transpose_prep<<<dim3(DD/32, DD/32, LL), 256, 0, stream>>>(Wk, wkT, DD, DD);
        transpose_prep<<<dim3(DD/32, DD/32, LL), 256, 0, stream>>>(Wv, wvT, DD, DD);
        transpose_prep<<<dim3(DD/32, DD/32, LL), 256, 0, stream>>>(Wo, woT, DD, DD);
        transpose_prep<<<dim3(DFF/32, DD/32, LL), 256, 0, stream>>>(Wff1, wf1T, DD, DFF);
        transpose_prep<<<dim3(DD/32, DFF/32, LL), 256, 0, stream>>>(Wff2, wf2T, DFF, DD);
        transpose_prep<<<dim3(DD/32, DD/32, NN), 256, 0, stream>>>(eW1, e1T, DD, DD);
        transpose_prep<<<dim3(DD/32, DD/32, 1), 256, 0, stream>>>(dpW, dpT, DD, DD);
        transpose_prep<<<dim3(DD/32, DD/32, 1), 256, 0, stream>>>(dcW, dcT, DD, DD);
    }

    encoder_kernel<<<(NTOK*DD + 255)/256, 256, 0, stream>>>(
        base_s, int_s, targ, maskv, encW, encB, X);

    for (int l = 0; l < LL; ++l) {
        const size_t od = (size_t)l*DD*DD, of1 = (size_t)l*DD*DFF;
        // Q, K, V, (later O): 8192x512x512
        launch_gemm<128,64,0,true,bf16>(p0, dim3(8,64,1), stream,
            X, Wq+od, wqT+od, bq+(size_t)l*DD, A1, DD, DD, DD, DD, DD, 0,0,0,0);
        launch_gemm<128,64,0,true,bf16>(p0, dim3(8,64,1), stream,
            X, Wk+od, wkT+od, bk+(size_t)l*DD, A2, DD, DD, DD, DD, DD, 0,0,0,0);
        launch_gemm<128,64,0,true,bf16>(p0, dim3(8,64,1), stream,
            X, Wv+od, wvT+od, bv+(size_t)l*DD, A3, DD, DD, DD, DD, DD, 0,0,0,0);

        attn_fused2<<<BB*HH*2, 256, 0, stream>>>(A1, A2, A3, A1);

        launch_gemm<128,64,0,true,bf16>(p0, dim3(8,64,1), stream,
            A1, Wo+od, woT+od, bo+(size_t)l*DD, A2, DD, DD, DD, DD, DD, 0,0,0,0);
        add_ln_kernel<<<NTOK, 256, 0, stream>>>(X, A2, ln1g+(size_t)l*DD, ln1b+(size_t)l*DD);

        if (big) {
            launch_gemm<128,128,1,true,bf16>(p0, dim3(16,64,1), stream,
                X, Wff1+of1, wf1T+of1, bff1+(size_t)l*DFF, Hid,
                DD, DD, DFF, DD, DFF, 0,0,0,0);
            launch_gemm<128,64,0,true,bf16>(p0, dim3(8,64,1), stream,
                Hid, Wff2+of1, wf2T+of1, bff2+(size_t)l*DD, Yb,
                DFF, DFF, DD, DFF, DD, 0,0,0,0);
            add_ln_kernel<<<NTOK, 256, 0, stream>>>(X, Yb, ln2g+(size_t)l*DD, ln2b+(size_t)l*DD);
        } else {
            for (int c = 0; c < 4; ++c) {
                launch_gemm<128,128,1,true,bf16>(p0, dim3(16,16,1), stream,
                    X + (size_t)c*2048*DD, Wff1+of1, wf1T+of1, bff1+(size_t)l*DFF, Hid,
                    DD, DD, DFF, DD, DFF, 0,0,0,0);
                launch_gemm<128,64,0,true,bf16>(p0, dim3(8,16,1), stream,
                    Hid, Wff2+of1, wf2T+of1, bff2+(size_t)l*DD, A3 + (size_t)c*2048*DD,
                    DFF, DFF, DD, DFF, DD, 0,0,0,0);
            }
            add_ln_kernel<<<NTOK, 256, 0, stream>>>(X, A3, ln2g+(size_t)l*DD, ln2b+(size_t)l*DD);
        }
    }

    // hyper-net modulation
    hyper_kernel<<<BB, 512, 0, stream>>>(nidx, emb, hW1, hb1, hW2, hb2, MODp);
    bf16* XMb = big ? Yb : A1;
    xm_kernel<<<(NTOK*DD + 255)/256, 256, 0, stream>>>(X, MODp, XMb);

    // per-node experts: grouped 64x512x512, out HE[n][b][d]
    bf16* HEb = big ? A1 : A2;
    launch_gemm<64,128,1,true,bf16>(p0, dim3(4,1,NN), stream,
        XMb, eW1, e1T, eb1, HEb, DD, NN*DD, DD, DD, DD,
        /*sAg=*/DD, /*sBg=*/(long long)DD*DD, /*sbg=*/DD, /*sCg=*/(long long)BB*DD);
    deltas_kernel<<<NN*BB, 256, 0, stream>>>(HEb, eW2, eb2, out_deltas);

    // DAG heads
    bf16* Pb = big ? A2 : A1;
    bf16* Cb = A3;
    launch_gemm<128,64,0,true,bf16>(p0, dim3(8,64,1), stream,
        X, dpW, dpT, dpB, Pb, DD, DD, DD, DD, DD, 0,0,0,0);
    launch_gemm<128,64,0,true,bf16>(p0, dim3(8,64,1), stream,
        X, dcW, dcT, dcB, Cb, DD, DD, DD, DD, DD, 0,0,0,0);
    // logits[b] = P[b] @ C[b]^T  (both bf16 activations -> TRANSB path)
    mfma_gemm<64,64,0,true,false,bf16,float><<<dim3(2,2,BB), 256, 0, stream>>>(
        Pb, Cb, (const float*)nullptr, out_logits, DD, DD, DD, NN,
        /*sAg=*/(long long)NN*DD, /*sBg=*/(long long)NN*DD, /*sbg=*/0,
        /*sCg=*/(long long)NN*NN);
    finalize_kernel<<<(BB*NN*NN + 255)/256, 256, 0, stream>>>(
        out_logits, gnoise, out_adj);

    (void)in_sizes; (void)n_in; (void)out_size;
}

// Round 5
// 1096.005 us; speedup vs baseline: 5.5320x; 1.4143x over previous
//
#include <hip/hip_runtime.h>
#include <hip/hip_bf16.h>
#include <math.h>

// ---- problem constants ----
#define BB 64
#define NN 128
#define DD 512
#define DFF 2048
#define HH 8
#define DHH 64
#define EE 32
#define HID 64
#define LL 4
#define NTOK (BB*NN)          // 8192

typedef __hip_bfloat16 bf16;
typedef __attribute__((ext_vector_type(8))) short short8v;   // 8 bf16 (4 VGPRs)
typedef __attribute__((ext_vector_type(4))) float f32x4v;    // 4 f32 acc

__device__ __forceinline__ float b2f(bf16 x) { return __bfloat162float(x); }
__device__ __forceinline__ bf16 f2b(float x) { return __float2bfloat16(x); }
__device__ __forceinline__ float gelu_f(float x) {
    return 0.5f * x * (1.0f + erff(x * 0.7071067811865476f));
}

union F4B8 { float4 f; bf16 h[8]; };
union B2U { bf16 h[2]; unsigned int u; };

// ---------------- weight prep: f32 [G][K][N] -> bf16 [G][N][K] ----------------
__global__ __launch_bounds__(256) void transpose_prep(
    const float* __restrict__ in, bf16* __restrict__ out, int K, int N)
{
    __shared__ float t[32][33];
    int g = blockIdx.z;
    in  += (size_t)g * K * N;
    out += (size_t)g * K * N;
    int n0 = blockIdx.x * 32, k0 = blockIdx.y * 32;
    int tx = threadIdx.x & 31, ty = threadIdx.x >> 5;   // ty in 0..7
#pragma unroll
    for (int i = 0; i < 32; i += 8)
        t[ty + i][tx] = in[(size_t)(k0 + ty + i) * N + n0 + tx];
    __syncthreads();
#pragma unroll
    for (int i = 0; i < 32; i += 8)
        out[(size_t)(n0 + ty + i) * K + k0 + tx] = f2b(t[tx][ty + i]);
}

// ---------------- encoder: feats[BN,4] @ enc_W[4,D] + enc_b (vectorized) ----
__global__ __launch_bounds__(256) void encoder_kernel(
    const float* __restrict__ bs, const float* __restrict__ ins,
    const float* __restrict__ tr, const float* __restrict__ im,
    const float* __restrict__ encW, const float* __restrict__ encB,
    bf16* __restrict__ X)
{
    int idx = blockIdx.x * 256 + threadIdx.x;       // 8 outputs per thread
    size_t i8 = (size_t)idx * 8;
    int d0 = (int)(i8 & (DD - 1));
    int t  = (int)(i8 >> 9);
    float f0 = bs[t], f1 = ins[t], f2 = tr[t], f3 = im[t];
    alignas(16) float acc[8], w[8];
    *(float4*)&acc[0] = *(const float4*)&encB[d0];
    *(float4*)&acc[4] = *(const float4*)&encB[d0 + 4];
    const float fs[4] = {f0, f1, f2, f3};
#pragma unroll
    for (int k = 0; k < 4; k++) {
        *(float4*)&w[0] = *(const float4*)&encW[k * DD + d0];
        *(float4*)&w[4] = *(const float4*)&encW[k * DD + d0 + 4];
#pragma unroll
        for (int j = 0; j < 8; j++) acc[j] = fmaf(fs[k], w[j], acc[j]);
    }
    F4B8 o;
#pragma unroll
    for (int j = 0; j < 8; j++) o.h[j] = f2b(acc[j]);
    *(float4*)&X[i8] = o.f;
}

// ---------------- MFMA GEMM (m97-class 4-wave 2x2) ----------------
template<int BM, int BN, int ACT, bool TRANSB, bool HAS_BIAS, typename TB, typename TC>
__global__ __launch_bounds__(256) void mfma_gemm(
    const bf16* __restrict__ A, const TB* __restrict__ Bw,
    const float* __restrict__ bias, TC* __restrict__ C,
    int K, int lda, int ldb, int ldc,
    long long sAg, long long sBg, long long sbg, long long sCg)
{
    constexpr int BK = 32;
    constexpr int LDK = BK + 8;
    constexpr int MI = BM / 32;
    constexpr int NI = BN / 32;
    __shared__ bf16 As[BM][LDK];
    __shared__ bf16 Bs[BN][LDK];
    const int g = blockIdx.z;
    const bf16* Ag = A + (size_t)g * sAg;
    const TB*   Bg = Bw + (size_t)g * sBg;
    const int m0 = blockIdx.y * BM;
    const int n0 = blockIdx.x * BN;
    const int tid = threadIdx.x;
    const int lane = tid & 63;
    const int wid = tid >> 6;
    const int wm = wid >> 1, wn = wid & 1;
    const int lr = lane & 15;
    const int lq = lane >> 4;

    f32x4v acc[MI][NI];
#pragma unroll
    for (int mi = 0; mi < MI; mi++)
#pragma unroll
        for (int ni = 0; ni < NI; ni++)
            acc[mi][ni] = (f32x4v){0.f, 0.f, 0.f, 0.f};

    for (int k0 = 0; k0 < K; k0 += BK) {
#pragma unroll
        for (int c = tid; c < BM * 4; c += 256) {
            int row = c >> 2, k8 = (c & 3) << 3;
            *(float4*)&As[row][k8] =
                *(const float4*)(Ag + (size_t)(m0 + row) * lda + k0 + k8);
        }
        if constexpr (TRANSB) {
#pragma unroll
            for (int c = tid; c < BN * 4; c += 256) {
                int row = c >> 2, k8 = (c & 3) << 3;
                *(float4*)&Bs[row][k8] =
                    *(const float4*)((const bf16*)Bg + (size_t)(n0 + row) * ldb + k0 + k8);
            }
        } else {
#pragma unroll
            for (int c = tid; c < BK * (BN / 4); c += 256) {
                int kk = c / (BN / 4);
                int n4 = (c % (BN / 4)) * 4;
                float4 v = *(const float4*)((const float*)Bg + (size_t)(k0 + kk) * ldb + n0 + n4);
                int kg = kk >> 3, kw = kk & 7;
                float vv[4] = {v.x, v.y, v.z, v.w};
#pragma unroll
                for (int i = 0; i < 4; i++) {
                    int n = n4 + i;
                    int col = ((kg ^ ((n >> 2) & 3)) << 3) | kw;
                    Bs[n][col] = f2b(vv[i]);
                }
            }
        }
        __syncthreads();
        short8v av[MI], bv[NI];
#pragma unroll
        for (int mi = 0; mi < MI; mi++) {
            int row = wm * (BM / 2) + mi * 16 + lr;
            av[mi] = *(const short8v*)&As[row][lq * 8];
        }
#pragma unroll
        for (int ni = 0; ni < NI; ni++) {
            int row = wn * (BN / 2) + ni * 16 + lr;
            int col = TRANSB ? (lq * 8) : (((lq ^ ((row >> 2) & 3)) << 3));
            bv[ni] = *(const short8v*)&Bs[row][col];
        }
#pragma unroll
        for (int mi = 0; mi < MI; mi++)
#pragma unroll
            for (int ni = 0; ni < NI; ni++)
                acc[mi][ni] = __builtin_amdgcn_mfma_f32_16x16x32_bf16(
                    av[mi], bv[ni], acc[mi][ni], 0, 0, 0);
        __syncthreads();
    }
    TC* Cg = C + (size_t)g * sCg;
#pragma unroll
    for (int mi = 0; mi < MI; mi++) {
        int rbase = m0 + wm * (BM / 2) + mi * 16 + lq * 4;
#pragma unroll
        for (int ni = 0; ni < NI; ni++) {
            int col = n0 + wn * (BN / 2) + ni * 16 + lr;
            float bvv = HAS_BIAS ? bias[(size_t)g * sbg + col] : 0.f;
#pragma unroll
            for (int r = 0; r < 4; r++) {
                float v = acc[mi][ni][r] + bvv;
                if (ACT == 1) v = gelu_f(v);
                if constexpr (sizeof(TC) == 2)
                    ((bf16*)Cg)[(size_t)(rbase + r) * ldc + col] = f2b(v);
                else
                    ((float*)Cg)[(size_t)(rbase + r) * ldc + col] = v;
            }
        }
    }
}

// ---------------- MFMA fused attention: one block per (b,h) ----------------
// 4 waves x 32 q-rows. QK^T frags direct from global; in-register softmax
// (reduce over lr lanes); P (bf16) -> LDS; V^T staged in LDS; PV via MFMA.
__global__ __launch_bounds__(256) void attn_mfma(
    const bf16* __restrict__ Q, const bf16* __restrict__ K,
    const bf16* __restrict__ V, bf16* __restrict__ O)
{
    __shared__ bf16 Ps[NN][NN + 8];     // 128 x 136
    __shared__ bf16 Vt[DHH][NN + 8];    // Vt[d][m], 64 x 136
    int bh = blockIdx.x;
    int h = bh & (HH - 1);
    int b = bh >> 3;
    const int tid = threadIdx.x;
    const int lane = tid & 63;
    const int w = tid >> 6;
    const int lr = lane & 15;
    const int lq = lane >> 4;
    const size_t baseQ = (size_t)(b * NN) * DD + h * DHH;

    // stage V^T: each task = (m,m+1) pair x 8 d's; u32-paired LDS writes
    for (int c = tid; c < 512; c += 256) {
        int m = (c >> 3) * 2;
        int d8 = (c & 7) * 8;
        F4B8 v0, v1;
        v0.f = *(const float4*)(V + baseQ + (size_t)m * DD + d8);
        v1.f = *(const float4*)(V + baseQ + (size_t)(m + 1) * DD + d8);
#pragma unroll
        for (int j = 0; j < 8; j++) {
            B2U pk; pk.h[0] = v0.h[j]; pk.h[1] = v1.h[j];
            *(unsigned int*)&Vt[d8 + j][m] = pk.u;
        }
    }

    // QK^T: S[32 x 128] per wave, K-frags direct from global
    f32x4v sacc[2][8];
#pragma unroll
    for (int mi = 0; mi < 2; mi++)
#pragma unroll
        for (int ni = 0; ni < 8; ni++)
            sacc[mi][ni] = (f32x4v){0.f, 0.f, 0.f, 0.f};
#pragma unroll
    for (int ks = 0; ks < 2; ks++) {
        short8v aq[2];
#pragma unroll
        for (int mi = 0; mi < 2; mi++) {
            int row = w * 32 + mi * 16 + lr;
            aq[mi] = *(const short8v*)(Q + baseQ + (size_t)row * DD + ks * 32 + lq * 8);
        }
#pragma unroll
        for (int ni = 0; ni < 8; ni++) {
            int col = ni * 16 + lr;
            short8v bk = *(const short8v*)(K + baseQ + (size_t)col * DD + ks * 32 + lq * 8);
#pragma unroll
            for (int mi = 0; mi < 2; mi++)
                sacc[mi][ni] = __builtin_amdgcn_mfma_f32_16x16x32_bf16(
                    aq[mi], bk, sacc[mi][ni], 0, 0, 0);
        }
    }

    // in-register softmax: row r held by 16 lanes (lr) x 8 ni regs
#pragma unroll
    for (int mi = 0; mi < 2; mi++) {
#pragma unroll
        for (int r = 0; r < 4; r++) {
            float mx = -1e30f;
#pragma unroll
            for (int ni = 0; ni < 8; ni++)
                mx = fmaxf(mx, sacc[mi][ni][r]);
            mx = fmaxf(mx, __shfl_xor(mx, 1, 64));
            mx = fmaxf(mx, __shfl_xor(mx, 2, 64));
            mx = fmaxf(mx, __shfl_xor(mx, 4, 64));
            mx = fmaxf(mx, __shfl_xor(mx, 8, 64));
            mx *= 0.125f;
            float s = 0.f;
#pragma unroll
            for (int ni = 0; ni < 8; ni++) {
                float e = __expf(sacc[mi][ni][r] * 0.125f - mx);
                sacc[mi][ni][r] = e; s += e;
            }
            s += __shfl_xor(s, 1, 64);
            s += __shfl_xor(s, 2, 64);
            s += __shfl_xor(s, 4, 64);
            s += __shfl_xor(s, 8, 64);
            float inv = 1.0f / s;
            int row = w * 32 + mi * 16 + lq * 4 + r;
#pragma unroll
            for (int ni = 0; ni < 8; ni++)
                Ps[row][ni * 16 + lr] = f2b(sacc[mi][ni][r] * inv);
        }
    }
    __syncthreads();   // Vt (cross-thread) + own P writes drained

    // PV: O[32 x 64] per wave
    f32x4v oacc[2][4];
#pragma unroll
    for (int mi = 0; mi < 2; mi++)
#pragma unroll
        for (int ni = 0; ni < 4; ni++)
            oacc[mi][ni] = (f32x4v){0.f, 0.f, 0.f, 0.f};
#pragma unroll
    for (int ks = 0; ks < 4; ks++) {
        short8v ap[2];
#pragma unroll
        for (int mi = 0; mi < 2; mi++)
            ap[mi] = *(const short8v*)&Ps[w * 32 + mi * 16 + lr][ks * 32 + lq * 8];
#pragma unroll
        for (int ni = 0; ni < 4; ni++) {
            short8v bv = *(const short8v*)&Vt[ni * 16 + lr][ks * 32 + lq * 8];
#pragma unroll
            for (int mi = 0; mi < 2; mi++)
                oacc[mi][ni] = __builtin_amdgcn_mfma_f32_16x16x32_bf16(
                    ap[mi], bv, oacc[mi][ni], 0, 0, 0);
        }
    }
#pragma unroll
    for (int mi = 0; mi < 2; mi++)
#pragma unroll
        for (int ni = 0; ni < 4; ni++) {
            int d = ni * 16 + lr;
#pragma unroll
            for (int r = 0; r < 4; r++) {
                int row = w * 32 + mi * 16 + lq * 4 + r;
                O[baseQ + (size_t)row * DD + d] = f2b(oacc[mi][ni][r]);
            }
        }
}

// ---------------- add+LN: one wave per token, shuffle-reduce ----------------
__global__ __launch_bounds__(256) void add_ln_kernel(
    bf16* __restrict__ X, const bf16* __restrict__ R,
    const float* __restrict__ g, const float* __restrict__ bt)
{
    int tok = blockIdx.x * 4 + (threadIdx.x >> 6);
    int lane = threadIdx.x & 63;
    size_t base = (size_t)tok * DD + lane * 8;
    F4B8 x, r;
    x.f = *(const float4*)&X[base];
    r.f = *(const float4*)&R[base];
    float v[8]; float s = 0.f, s2 = 0.f;
#pragma unroll
    for (int j = 0; j < 8; j++) {
        v[j] = b2f(x.h[j]) + b2f(r.h[j]);
        s += v[j]; s2 += v[j] * v[j];
    }
#pragma unroll
    for (int m = 1; m < 64; m <<= 1) {
        s  += __shfl_xor(s, m, 64);
        s2 += __shfl_xor(s2, m, 64);
    }
    float mean = s * (1.0f / 512.0f);
    float var = fmaxf(s2 * (1.0f / 512.0f) - mean * mean, 0.0f);
    float rstd = rsqrtf(var + 1e-5f);
    alignas(16) float gv[8], bv[8];
    *(float4*)&gv[0] = *(const float4*)&g[lane * 8];
    *(float4*)&gv[4] = *(const float4*)&g[lane * 8 + 4];
    *(float4*)&bv[0] = *(const float4*)&bt[lane * 8];
    *(float4*)&bv[4] = *(const float4*)&bt[lane * 8 + 4];
    F4B8 o;
#pragma unroll
    for (int j = 0; j < 8; j++)
        o.h[j] = f2b((v[j] - mean) * rstd * gv[j] + bv[j]);
    *(float4*)&X[base] = o.f;
}

// ---------------- hyper-network ----------------
__global__ __launch_bounds__(512) void hyper_kernel(
    const int* __restrict__ idx, const float* __restrict__ emb,
    const float* __restrict__ W1, const float* __restrict__ b1,
    const float* __restrict__ W2, const float* __restrict__ b2,
    float* __restrict__ MODp)
{
    int b = blockIdx.x;
    int t = threadIdx.x;
    __shared__ float instr[EE];
    __shared__ float h1[HID];
    int id = idx[b];
    if (t < EE) instr[t] = emb[id*EE + t];
    __syncthreads();
    if (t < HID) {
        float a = b1[t];
        for (int i = 0; i < EE; i++) a += instr[i] * W1[i*HID + t];
        h1[t] = gelu_f(a);
    }
    __syncthreads();
    float a = b2[t];
    for (int i = 0; i < HID; i++) a += h1[i] * W2[i*DD + t];
    MODp[(size_t)b*DD + t] = a;
}

// ---------------- xm = x * mod[b] (vectorized) ----------------
__global__ __launch_bounds__(256) void xm_kernel(
    const bf16* __restrict__ X, const float* __restrict__ MODp,
    bf16* __restrict__ XM)
{
    int idx = blockIdx.x * 256 + threadIdx.x;
    size_t i8 = (size_t)idx * 8;
    int b = (int)(i8 >> 16);
    int d0 = (int)(i8 & (DD - 1));
    F4B8 x; x.f = *(const float4*)&X[i8];
    alignas(16) float mv[8];
    *(float4*)&mv[0] = *(const float4*)&MODp[b * DD + d0];
    *(float4*)&mv[4] = *(const float4*)&MODp[b * DD + d0 + 4];
    F4B8 o;
#pragma unroll
    for (int j = 0; j < 8; j++) o.h[j] = f2b(b2f(x.h[j]) * mv[j]);
    *(float4*)&XM[i8] = o.f;
}

// ---------------- deltas: one wave per (n,b) row ----------------
__global__ __launch_bounds__(256) void deltas_kernel(
    const bf16* __restrict__ HE, const float* __restrict__ W2,
    const float* __restrict__ b2, float* __restrict__ out)
{
    int rid = blockIdx.x * 4 + (threadIdx.x >> 6);   // n*64 + b
    int lane = threadIdx.x & 63;
    int n = rid >> 6;
    int b = rid & 63;
    const bf16* hrow = HE + ((size_t)n * BB + b) * DD + lane * 8;
    const float* wrow = W2 + (size_t)n * DD + lane * 8;
    F4B8 hv; hv.f = *(const float4*)hrow;
    alignas(16) float wv[8];
    *(float4*)&wv[0] = *(const float4*)&wrow[0];
    *(float4*)&wv[4] = *(const float4*)&wrow[4];
    float s = 0.f;
#pragma unroll
    for (int j = 0; j < 8; j++) s += b2f(hv.h[j]) * wv[j];
#pragma unroll
    for (int m = 1; m < 64; m <<= 1) s += __shfl_xor(s, m, 64);
    if (lane == 0) out[b * NN + n] = s + b2[n];
}

// ---------------- adj = sigmoid(logits + noise) (vectorized) ----------------
__global__ __launch_bounds__(256) void finalize_kernel(
    const float* __restrict__ lg, const float* __restrict__ gn,
    float* __restrict__ out_adj)
{
    int idx = blockIdx.x * 256 + threadIdx.x;
    size_t i4 = (size_t)idx * 4;
    float4 l = *(const float4*)&lg[i4];
    float4 n = *(const float4*)&gn[i4];
    float4 o;
    o.x = 1.0f / (1.0f + __expf(-(l.x + n.x)));
    o.y = 1.0f / (1.0f + __expf(-(l.y + n.y)));
    o.z = 1.0f / (1.0f + __expf(-(l.z + n.z)));
    o.w = 1.0f / (1.0f + __expf(-(l.w + n.w)));
    *(float4*)&out_adj[i4] = o;
}

// ---------------- host-side GEMM dispatch helper ----------------
template<int BM, int BN, int ACT, bool HB, typename TC>
static inline void launch_gemm(bool p0, dim3 grid, hipStream_t s,
    const bf16* A, const float* Wf, const bf16* Wt, const float* bias, TC* C,
    int K, int lda, int ldbF, int ldbT, int ldc,
    long long sAg, long long sBg, long long sbg, long long sCg)
{
    if (p0)
        mfma_gemm<BM,BN,ACT,true ,HB,bf16 ,TC><<<grid,256,0,s>>>(A, Wt, bias, C, K, lda, ldbT, ldc, sAg,sBg,sbg,sCg);
    else
        mfma_gemm<BM,BN,ACT,false,HB,float,TC><<<grid,256,0,s>>>(A, Wf, bias, C, K, lda, ldbF, ldc, sAg,sBg,sbg,sCg);
}

// =========================== host side ===========================
extern "C" void kernel_launch(void* const* d_in, const int* in_sizes, int n_in,
                              void* d_out, int out_size, void* d_ws, size_t ws_size,
                              hipStream_t stream)
{
    const float* base_s = (const float*)d_in[0];
    const float* int_s  = (const float*)d_in[1];
    const float* targ   = (const float*)d_in[2];
    const float* maskv  = (const float*)d_in[3];
    const int*   nidx   = (const int*)  d_in[4];
    const float* gnoise = (const float*)d_in[5];
    const float* encW = (const float*)d_in[6];
    const float* encB = (const float*)d_in[7];
    const float* Wq = (const float*)d_in[8];  const float* bq = (const float*)d_in[9];
    const float* Wk = (const float*)d_in[10]; const float* bk = (const float*)d_in[11];
    const float* Wv = (const float*)d_in[12]; const float* bv = (const float*)d_in[13];
    const float* Wo = (const float*)d_in[14]; const float* bo = (const float*)d_in[15];
    const float* ln1g = (const float*)d_in[16]; const float* ln1b = (const float*)d_in[17];
    const float* Wff1 = (const float*)d_in[18]; const float* bff1 = (const float*)d_in[19];
    const float* Wff2 = (const float*)d_in[20]; const float* bff2 = (const float*)d_in[21];
    const float* ln2g = (const float*)d_in[22]; const float* ln2b = (const float*)d_in[23];
    const float* emb  = (const float*)d_in[24];
    const float* hW1 = (const float*)d_in[25]; const float* hb1 = (const float*)d_in[26];
    const float* hW2 = (const float*)d_in[27]; const float* hb2 = (const float*)d_in[28];
    const float* eW1 = (const float*)d_in[29]; const float* eb1 = (const float*)d_in[30];
    const float* eW2 = (const float*)d_in[31]; const float* eb2 = (const float*)d_in[32];
    const float* dpW = (const float*)d_in[33]; const float* dpB = (const float*)d_in[34];
    const float* dcW = (const float*)d_in[35]; const float* dcB = (const float*)d_in[36];

    float* out_deltas = (float*)d_out;
    float* out_logits = out_deltas + (size_t)BB*NN;
    float* out_adj    = out_logits + (size_t)BB*NN*NN;

    const size_t SZ = (size_t)NTOK * DD;     // 4,194,304 elements

    // workspace tiering (expert weights NOT transposed — single-use, no reuse)
    const size_t NEED_P1 = 6*SZ*2 + (size_t)BB*DD*4;                    // 50.5 MB
    const size_t WT_ELEMS = (size_t)4*LL*DD*DD + 2*(size_t)LL*DD*DFF
                          + 2*(size_t)DD*DD;                            // 13,107,200
    const size_t NEED_P0 = NEED_P1 + WT_ELEMS*2;                        // ~76.7 MB
    const bool p0  = ws_size >= NEED_P0;
    const bool big = ws_size >= NEED_P1;

    bf16* X = (bf16*)d_ws;
    bf16 *A1, *A2, *A3, *Hid, *Yb;
    float* MODp;
    if (big) {
        bf16* H0 = X + SZ;
        A1 = H0; A2 = H0 + SZ; A3 = H0 + 2*SZ;
        Hid = H0;                    // full 8192 x 2048 hidden
        Yb  = H0 + 4*SZ;
        MODp = (float*)(Yb + SZ);
    } else {
        A1 = X + SZ; A2 = A1 + SZ; A3 = A2 + SZ;
        Hid = A2; Yb = nullptr;
        MODp = (float*)(A3 + SZ);
    }

    bf16 *wqT=nullptr,*wkT=nullptr,*wvT=nullptr,*woT=nullptr,
         *wf1T=nullptr,*wf2T=nullptr,*dpT=nullptr,*dcT=nullptr;
    if (p0) {
        bf16* WT = (bf16*)(MODp + (size_t)BB*DD);
        wqT = WT;                         wkT = wqT + (size_t)LL*DD*DD;
        wvT = wkT + (size_t)LL*DD*DD;     woT = wvT + (size_t)LL*DD*DD;
        wf1T = woT + (size_t)LL*DD*DD;    wf2T = wf1T + (size_t)LL*DD*DFF;
        dpT = wf2T + (size_t)LL*DD*DFF;   dcT = dpT + (size_t)DD*DD;

        transpose_prep<<<dim3(DD/32, DD/32, LL), 256, 0, stream>>>(Wq, wqT, DD, DD);
        transpose_prep<<<dim3(DD/32, DD/32, LL), 256, 0, stream>>>(Wk, wkT, DD, DD);
        transpose_prep<<<dim3(DD/32, DD/32, LL), 256, 0, stream>>>(Wv, wvT, DD, DD);
        transpose_prep<<<dim3(DD/32, DD/32, LL), 256, 0, stream>>>(Wo, woT, DD, DD);
        transpose_prep<<<dim3(DFF/32, DD/32, LL), 256, 0, stream>>>(Wff1, wf1T, DD, DFF);
        transpose_prep<<<dim3(DD/32, DFF/32, LL), 256, 0, stream>>>(Wff2, wf2T, DFF, DD);
        transpose_prep<<<dim3(DD/32, DD/32, 1), 256, 0, stream>>>(dpW, dpT, DD, DD);
        transpose_prep<<<dim3(DD/32, DD/32, 1), 256, 0, stream>>>(dcW, dcT, DD, DD);
    }

    encoder_kernel<<<NTOK*DD/8/256, 256, 0, stream>>>(
        base_s, int_s, targ, maskv, encW, encB, X);

    for (int l = 0; l < LL; ++l) {
        const size_t od = (size_t)l*DD*DD, of1 = (size_t)l*DD*DFF;
        launch_gemm<128,128,0,true,bf16>(p0, dim3(4,64,1), stream,
            X, Wq+od, wqT+od, bq+(size_t)l*DD, A1, DD, DD, DD, DD, DD, 0,0,0,0);
        launch_gemm<128,128,0,true,bf16>(p0, dim3(4,64,1), stream,
            X, Wk+od, wkT+od, bk+(size_t)l*DD, A2, DD, DD, DD, DD, DD, 0,0,0,0);
        launch_gemm<128,128,0,true,bf16>(p0, dim3(4,64,1), stream,
            X, Wv+od, wvT+od, bv+(size_t)l*DD, A3, DD, DD, DD, DD, DD, 0,0,0,0);

        attn_mfma<<<BB*HH, 256, 0, stream>>>(A1, A2, A3, A1);

        launch_gemm<128,128,0,true,bf16>(p0, dim3(4,64,1), stream,
            A1, Wo+od, woT+od, bo+(size_t)l*DD, A2, DD, DD, DD, DD, DD, 0,0,0,0);
        add_ln_kernel<<<NTOK/4, 256, 0, stream>>>(X, A2, ln1g+(size_t)l*DD, ln1b+(size_t)l*DD);

        if (big) {
            launch_gemm<128,128,1,true,bf16>(p0, dim3(16,64,1), stream,
                X, Wff1+of1, wf1T+of1, bff1+(size_t)l*DFF, Hid,
                DD, DD, DFF, DD, DFF, 0,0,0,0);
            launch_gemm<128,128,0,true,bf16>(p0, dim3(4,64,1), stream,
                Hid, Wff2+of1, wf2T+of1, bff2+(size_t)l*DD, Yb,
                DFF, DFF, DD, DFF, DD, 0,0,0,0);
            add_ln_kernel<<<NTOK/4, 256, 0, stream>>>(X, Yb, ln2g+(size_t)l*DD, ln2b+(size_t)l*DD);
        } else {
            for (int c = 0; c < 4; ++c) {
                launch_gemm<128,128,1,true,bf16>(p0, dim3(16,16,1), stream,
                    X + (size_t)c*2048*DD, Wff1+of1, wf1T+of1, bff1+(size_t)l*DFF, Hid,
                    DD, DD, DFF, DD, DFF, 0,0,0,0);
                launch_gemm<128,128,0,true,bf16>(p0, dim3(4,16,1), stream,
                    Hid, Wff2+of1, wf2T+of1, bff2+(size_t)l*DD, A3 + (size_t)c*2048*DD,
                    DFF, DFF, DD, DFF, DD, 0,0,0,0);
            }
            add_ln_kernel<<<NTOK/4, 256, 0, stream>>>(X, A3, ln2g+(size_t)l*DD, ln2b+(size_t)l*DD);
        }
    }

    hyper_kernel<<<BB, 512, 0, stream>>>(nidx, emb, hW1, hb1, hW2, hb2, MODp);
    bf16* XMb = big ? Yb : A1;
    xm_kernel<<<NTOK*DD/8/256, 256, 0, stream>>>(X, MODp, XMb);

    // per-node experts: grouped 64x512x512, f32 weight path (no transpose —
    // each group's weight is read by exactly one block; transpose is pure cost)
    bf16* HEb = big ? A1 : A2;
    mfma_gemm<64,128,1,false,true,float,bf16><<<dim3(4,1,NN), 256, 0, stream>>>(
        XMb, eW1, eb1, HEb, DD, NN*DD, DD, DD,
        /*sAg=*/DD, /*sBg=*/(long long)DD*DD, /*sbg=*/DD, /*sCg=*/(long long)BB*DD);
    deltas_kernel<<<NN*BB/4, 256, 0, stream>>>(HEb, eW2, eb2, out_deltas);

    // DAG heads
    bf16* Pb = big ? A2 : A1;
    bf16* Cb = A3;
    launch_gemm<128,128,0,true,bf16>(p0, dim3(4,64,1), stream,
        X, dpW, dpT, dpB, Pb, DD, DD, DD, DD, DD, 0,0,0,0);
    launch_gemm<128,128,0,true,bf16>(p0, dim3(4,64,1), stream,
        X, dcW, dcT, dcB, Cb, DD, DD, DD, DD, DD, 0,0,0,0);
    // logits[b] = P[b] @ C[b]^T, f32 straight into d_out
    mfma_gemm<64,64,0,true,false,bf16,float><<<dim3(2,2,BB), 256, 0, stream>>>(
        Pb, Cb, (const float*)nullptr, out_logits, DD, DD, DD, NN,
        /*sAg=*/(long long)NN*DD, /*sBg=*/(long long)NN*DD, /*sbg=*/0,
        /*sCg=*/(long long)NN*NN);
    finalize_kernel<<<BB*NN*NN/4/256, 256, 0, stream>>>(
        out_logits, gnoise, out_adj);

    (void)in_sizes; (void)n_in; (void)out_size;
}